// Round 4
// baseline (183.839 us; speedup 1.0000x reference)
//
#include <hip/hip_runtime.h>

#define SS 2
#define BB 16
#define KK 128
#define HH 128
#define WW 128
#define HWSZ (HH*WW)
#define EPSF 1e-6f
#define MAXD 181.01933598375618f
#define MAXD2 32768.0f

// ws layout (floats): [0,4096) sumpow[(s*B+b)*K+k], [4096,4128) t1num[s*B+b], [4128,4160) nest[s*B+b]

__device__ __forceinline__ float sigclip(float x) {
    float e = __expf(-x);
    float p = __builtin_amdgcn_rcpf(1.0f + e);
    return fminf(fmaxf(p, 1e-4f), 0.9999f);
}

__global__ void kzero(float* ws, float* out) {
    int i = blockIdx.x * 256 + threadIdx.x;
    if (i < 4160) ws[i] = 0.0f;
    if (i < 3) out[i] = 0.0f;
}

// Fused WHD kernel: one block per (b, 2-row chunk of 256 pixels).
// Phase 1 (term2): thread=(k,half), RAW points (mask applied in kC, as in ref).
// Phase 2 (term1): thread=pixel, MASKED points (1e9 -> excluded from min).
__global__ void __launch_bounds__(256) kAB(const float* __restrict__ hm,
                                           const int* __restrict__ ctr,
                                           const int* __restrict__ reg_mask,
                                           float* __restrict__ ws) {
    const int b = blockIdx.y;
    const int chunk = blockIdx.x;          // 0..63, rows 2c and 2c+1
    const int base = chunk * 256;
    const int tid = threadIdx.x;
    __shared__ float2 spp[256];            // (p0,p1) per pixel of the chunk
    __shared__ float2 spts_raw[KK];        // raw points (y,x) for term2
    __shared__ float2 spts_msk[KK];        // masked points for term1 min
    __shared__ float red0[KK], red1[KK];

    float p0 = sigclip(hm[(size_t)(0 * BB + b) * HWSZ + base + tid]);
    float p1 = sigclip(hm[(size_t)(1 * BB + b) * HWSZ + base + tid]);
    spp[tid] = make_float2(p0, p1);
    if (tid < KK) {
        int mk = reg_mask[b * KK + tid];
        float py = (float)ctr[(b * KK + tid) * 2 + 1];   // pts = ctr[...,::-1]
        float px = (float)ctr[(b * KK + tid) * 2 + 0];
        spts_raw[tid] = make_float2(py, px);
        spts_msk[tid] = mk ? make_float2(py, px) : make_float2(1e9f, 1e9f);
    }
    __syncthreads();

    // ---- phase 1: term2 partial sum_i (weighted+EPS)^-9 for point k, row (2c+half)
    const int k = tid & 127;
    const int half = tid >> 7;
    float2 pt = spts_raw[k];
    float fy1 = (float)(chunk * 2 + half);
    float dy2 = (fy1 - pt.x) * (fy1 - pt.x);
    float acc0 = 0.f, acc1 = 0.f;
    float dx = -pt.y;
    const float2* sp = &spp[half * 128];
    #pragma unroll 4
    for (int j = 0; j < 128; ++j) {
        float d = __builtin_amdgcn_sqrtf(fmaf(dx, dx, dy2));
        float t = d - MAXD;                  // weighted = maxd + p*(d-maxd)
        float2 p = sp[j];                    // LDS broadcast
        float w0 = fmaf(p.x, t, MAXD) + EPSF;
        float w1 = fmaf(p.y, t, MAXD) + EPSF;
        float a2 = w0 * w0, a4 = a2 * a2, a8 = a4 * a4;
        float b2 = w1 * w1, b4 = b2 * b2, b8 = b4 * b4;
        acc0 += __builtin_amdgcn_rcpf(a8 * w0);   // x^-9
        acc1 += __builtin_amdgcn_rcpf(b8 * w1);
        dx += 1.0f;
    }

    // ---- phase 2: term1 for pixel (base+tid); 4 independent min chains
    {
        float fy = (float)(chunk * 2 + (tid >> 7));
        float fx = (float)(tid & 127);
        float m0 = MAXD2, m1 = MAXD2, m2 = MAXD2, m3 = MAXD2;
        #pragma unroll 4
        for (int kk = 0; kk < KK; kk += 4) {
            float2 q0 = spts_msk[kk + 0];
            float2 q1 = spts_msk[kk + 1];
            float2 q2 = spts_msk[kk + 2];
            float2 q3 = spts_msk[kk + 3];
            float dy0 = fy - q0.x, dx0 = fx - q0.y;
            float dy1 = fy - q1.x, dx1 = fx - q1.y;
            float dy2_ = fy - q2.x, dx2 = fx - q2.y;
            float dy3 = fy - q3.x, dx3 = fx - q3.y;
            m0 = fminf(m0, fmaf(dx0, dx0, dy0 * dy0));
            m1 = fminf(m1, fmaf(dx1, dx1, dy1 * dy1));
            m2 = fminf(m2, fmaf(dx2, dx2, dy2_ * dy2_));
            m3 = fminf(m3, fmaf(dx3, dx3, dy3 * dy3));
        }
        float dmin = __builtin_amdgcn_sqrtf(fminf(fminf(m0, m1), fminf(m2, m3)));
        float t1a = p0 * dmin, t1b = p1 * dmin, nea = p0, neb = p1;
        #pragma unroll
        for (int off = 32; off > 0; off >>= 1) {
            t1a += __shfl_down(t1a, off, 64);
            t1b += __shfl_down(t1b, off, 64);
            nea += __shfl_down(nea, off, 64);
            neb += __shfl_down(neb, off, 64);
        }
        if ((tid & 63) == 0) {
            atomicAdd(&ws[4096 + 0 * BB + b], t1a);
            atomicAdd(&ws[4096 + 1 * BB + b], t1b);
            atomicAdd(&ws[4128 + 0 * BB + b], nea);
            atomicAdd(&ws[4128 + 1 * BB + b], neb);
        }
    }

    // ---- phase 1 cross-half reduction + atomic
    if (half) { red0[k] = acc0; red1[k] = acc1; }
    __syncthreads();
    if (!half) {
        atomicAdd(&ws[(0 * BB + b) * KK + k], acc0 + red0[k]);
        atomicAdd(&ws[(1 * BB + b) * KK + k], acc1 + red1[k]);
    }
}

__device__ __forceinline__ float smoothl1(float l) {
    return (l < 0.2f) ? (2.5f * l * l) : (l - 0.1f);
}

// finalize: minn, term2, term1, bounded-IoU, compose outputs. One block per (s,b).
__global__ void __launch_bounds__(128) kC(const float* __restrict__ ws,
                                          const float* __restrict__ wh_map,
                                          const float* __restrict__ reg_map,
                                          const float* __restrict__ reg_gt,
                                          const float* __restrict__ wh_gt,
                                          const int* __restrict__ ind,
                                          const int* __restrict__ reg_mask,
                                          float* __restrict__ out) {
    const int b = blockIdx.x, s = blockIdx.y, k = threadIdx.x;
    float mk = (float)reg_mask[b * KK + k];
    float sp = ws[(s * BB + b) * KK + k];
    float mean = sp * (1.0f / 16384.0f);
    // select (not multiply) so a degenerate mean for masked k can't make NaN
    float c2 = (mk > 0.f) ? exp2f(log2f(mean) * (-1.0f / 9.0f)) : 0.0f;

    int idx = ind[b * KK + k];
    size_t sb = (size_t)(s * BB + b);
    float rp0 = reg_map[(sb * 2 + 0) * HWSZ + idx];
    float rp1 = reg_map[(sb * 2 + 1) * HWSZ + idx];
    float wp0 = wh_map[(sb * 2 + 0) * HWSZ + idx];
    float wp1 = wh_map[(sb * 2 + 1) * HWSZ + idx];
    float rg0 = reg_gt[(b * KK + k) * 2 + 0];
    float rg1 = reg_gt[(b * KK + k) * 2 + 1];
    float wg0 = wh_gt[(b * KK + k) * 2 + 0];
    float wg1 = wh_gt[(b * KK + k) * 2 + 1];
    float adx = fabsf(rg0 - rp0), ady = fabsf(rg1 - rp1);
    float ldx = 1.0f - fmaxf((wg0 - 2.0f * adx) / (wg0 + 2.0f * adx + EPSF), 0.0f);
    float ldy = 1.0f - fmaxf((wg1 - 2.0f * ady) / (wg1 + 2.0f * ady + EPSF), 0.0f);
    float ldw = 1.0f - fminf(wg0 / (wp0 + EPSF), wp0 / (wg0 + EPSF));
    float ldh = 1.0f - fminf(wg1 / (wp1 + EPSF), wp1 / (wg1 + EPSF));
    float lsum = (smoothl1(ldx) + smoothl1(ldy) + smoothl1(ldw) + smoothl1(ldh)) * mk;

    #pragma unroll
    for (int off = 32; off > 0; off >>= 1) {
        c2   += __shfl_down(c2, off, 64);
        lsum += __shfl_down(lsum, off, 64);
        mk   += __shfl_down(mk, off, 64);
    }
    __shared__ float sred[6];
    int lane = k & 63, wv = k >> 6;
    if (lane == 0) { sred[wv * 3 + 0] = c2; sred[wv * 3 + 1] = lsum; sred[wv * 3 + 2] = mk; }
    __syncthreads();
    if (k == 0) {
        float C2 = sred[0] + sred[3];
        float LS = sred[1] + sred[4];
        float MS = sred[2] + sred[5];
        float valid = (MS > 0.f) ? 1.f : 0.f;
        float den = fmaxf(MS, 1.f);
        float t1 = ws[4096 + s * BB + b] / (ws[4128 + s * BB + b] + EPSF);
        float t2 = C2 / den;
        float hmterm  = (t1 + t2) * valid * (1.0f / 32.0f);
        float iouterm = (LS / (den * 4.0f)) * valid * (1.0f / 32.0f);
        atomicAdd(&out[1], hmterm);
        atomicAdd(&out[2], iouterm);
        atomicAdd(&out[0], hmterm + 0.1f * iouterm);   // HM_WEIGHT=1, WH_WEIGHT=0.1
    }
}

extern "C" void kernel_launch(void* const* d_in, const int* in_sizes, int n_in,
                              void* d_out, int out_size, void* d_ws, size_t ws_size,
                              hipStream_t stream) {
    const float* hm       = (const float*)d_in[0];
    const float* wh_map   = (const float*)d_in[1];
    const float* reg_map  = (const float*)d_in[2];
    const float* reg_gt   = (const float*)d_in[3];
    const float* wh_gt    = (const float*)d_in[4];
    const int*   ind      = (const int*)d_in[5];
    const int*   ctr      = (const int*)d_in[6];
    const int*   reg_mask = (const int*)d_in[7];
    float* out = (float*)d_out;
    float* ws  = (float*)d_ws;

    hipLaunchKernelGGL(kzero, dim3(17), dim3(256), 0, stream, ws, out);
    hipLaunchKernelGGL(kAB, dim3(64, BB), dim3(256), 0, stream, hm, ctr, reg_mask, ws);
    hipLaunchKernelGGL(kC, dim3(BB, SS), dim3(128), 0, stream,
                       ws, wh_map, reg_map, reg_gt, wh_gt, ind, reg_mask, out);
}

// Round 5
// 97.663 us; speedup vs baseline: 1.8824x; 1.8824x over previous
//
#include <hip/hip_runtime.h>

#define SS 2
#define BB 16
#define KK 128
#define HH 128
#define WW 128
#define HWSZ (HH*WW)
#define EPSF 1e-6f
#define MAXD 181.01933598375618f
#define MAXD2 32768.0f
#define MAXD8 (181.01933598375618f * 0.125f)
#define ME8C ((181.01933598375618f + 1e-6f) * 0.125f)

typedef float v2f __attribute__((ext_vector_type(2)));

// ---------------- partial-slot (no-atomic) path layout -------------------
// wsP: [0, 524288) floats: sumpow partial  ws[((b*128 + row)*2 + s)*128 + k]
// wsQ: [524288, 532480): float4 per (b,row): {t1a, t1b, nea, neb}
#define WSQ_OFF 524288
#define WS_NEEDED_BYTES ((size_t)(524288 + 16*128*4) * 4)

__device__ __forceinline__ float sigclip(float x) {
    float e = __expf(-x);
    float p = __builtin_amdgcn_rcpf(1.0f + e);
    return fminf(fmaxf(p, 1e-4f), 0.9999f);
}

__device__ __forceinline__ float smoothl1(float l) {
    return (l < 0.2f) ? (2.5f * l * l) : (l - 0.1f);
}

// ======================= fast path: 2 launches ===========================

// One block per (b, row). 256 threads.
// Phase 1 (term2): thread=(k, col-half), 64 cols each, scaled-coord math, RAW pts.
// Phase 2 (term1): thread=(pixel, k-half), 64 pts each, MASKED pts, LDS combine.
__global__ void __launch_bounds__(256, 6) kAB2(const float* __restrict__ hm,
                                               const int* __restrict__ ctr,
                                               const int* __restrict__ reg_mask,
                                               float* __restrict__ ws,
                                               float* __restrict__ out) {
    const int r = blockIdx.x;            // row 0..127
    const int b = blockIdx.y;
    const int t = threadIdx.x;
    __shared__ __align__(16) float spp2[128][2];   // [col][channel]
    __shared__ float2 spts_raw[KK];
    __shared__ float2 spts_msk[KK];
    __shared__ float red0[KK], red1[KK];
    __shared__ float st2[128];
    __shared__ float sred[8];

    if (r == 0 && b == 0 && t < 3) out[t] = 0.0f;   // zero out for kC2 (stream-ordered)

    {   // stage probs: thread t -> channel c=t>>7, column j=t&127
        int c = t >> 7, j = t & 127;
        spp2[j][c] = sigclip(hm[(size_t)(c * BB + b) * HWSZ + r * WW + j]);
    }
    if (t < KK) {
        int mk = reg_mask[b * KK + t];
        float py = (float)ctr[(b * KK + t) * 2 + 1];   // pts = ctr[...,::-1]
        float px = (float)ctr[(b * KK + t) * 2 + 0];
        spts_raw[t] = make_float2(py, px);
        spts_msk[t] = mk ? make_float2(py, px) : make_float2(1e9f, 1e9f);
    }
    __syncthreads();

    const int k = t & 127;
    const int h = t >> 7;

    // ---- phase 1: coords pre-scaled by 0.125; w' = 0.125*(weighted+EPS)
    float acc0 = 0.f, acc1 = 0.f;
    {
        float2 pt = spts_raw[k];
        float dy = ((float)r - pt.x) * 0.125f;
        float dy2 = dy * dy;
        float dx = ((float)(h * 64) - pt.y) * 0.125f;
        const float4* sp4 = (const float4*)(&spp2[h * 64][0]);   // 2 cols per float4
        const v2f ME8V = {ME8C, ME8C};
        #pragma unroll 4
        for (int q = 0; q < 32; ++q) {
            float4 pq = sp4[q];
            float dA = __builtin_amdgcn_sqrtf(fmaf(dx, dx, dy2));
            float dxB = dx + 0.125f;
            float dB = __builtin_amdgcn_sqrtf(fmaf(dxB, dxB, dy2));
            float tA = dA - MAXD8;
            float tB = dB - MAXD8;
            v2f pA = {pq.x, pq.y};
            v2f pB = {pq.z, pq.w};
            v2f wA = pA * tA + ME8V;     // -> v_pk_fma_f32
            v2f wB = pB * tB + ME8V;
            v2f a2 = wA * wA, a4 = a2 * a2, a8 = a4 * a4, a9 = a8 * wA;
            v2f b2 = wB * wB, b4 = b2 * b2, b8 = b4 * b4, b9 = b8 * wB;
            acc0 += __builtin_amdgcn_rcpf(a9.x);
            acc1 += __builtin_amdgcn_rcpf(a9.y);
            acc0 += __builtin_amdgcn_rcpf(b9.x);
            acc1 += __builtin_amdgcn_rcpf(b9.y);
            dx += 0.25f;
        }
    }

    // ---- phase 2: half the k-range per thread (unscaled coords)
    float mm;
    {
        int pix = t & 127;
        float fx = (float)pix, fyf = (float)r;
        float m0 = MAXD2, m1 = MAXD2, m2 = MAXD2, m3 = MAXD2;
        int kb = h * 64;
        #pragma unroll 4
        for (int kk = 0; kk < 64; kk += 4) {
            float2 q0 = spts_msk[kb + kk + 0];
            float2 q1 = spts_msk[kb + kk + 1];
            float2 q2 = spts_msk[kb + kk + 2];
            float2 q3 = spts_msk[kb + kk + 3];
            float e0 = fyf - q0.x, f0 = fx - q0.y;
            float e1 = fyf - q1.x, f1 = fx - q1.y;
            float e2 = fyf - q2.x, f2 = fx - q2.y;
            float e3 = fyf - q3.x, f3 = fx - q3.y;
            m0 = fminf(m0, fmaf(f0, f0, e0 * e0));
            m1 = fminf(m1, fmaf(f1, f1, e1 * e1));
            m2 = fminf(m2, fmaf(f2, f2, e2 * e2));
            m3 = fminf(m3, fmaf(f3, f3, e3 * e3));
        }
        mm = fminf(fminf(m0, m1), fminf(m2, m3));
    }

    if (t >= 128) { st2[k] = mm; red0[k] = acc0; red1[k] = acc1; }
    __syncthreads();

    if (t < 128) {
        // sumpow partial store (coalesced over k)
        float s0 = acc0 + red0[k];
        float s1 = acc1 + red1[k];
        size_t basep = ((size_t)(b * 128 + r) * 2) * 128;
        ws[basep + k] = s0;
        ws[basep + 128 + k] = s1;
        // term1
        float dmin = __builtin_amdgcn_sqrtf(fminf(mm, st2[k]));
        float p0 = spp2[k][0], p1 = spp2[k][1];
        float t1a = p0 * dmin, t1b = p1 * dmin, nea = p0, neb = p1;
        #pragma unroll
        for (int off = 32; off > 0; off >>= 1) {
            t1a += __shfl_down(t1a, off, 64);
            t1b += __shfl_down(t1b, off, 64);
            nea += __shfl_down(nea, off, 64);
            neb += __shfl_down(neb, off, 64);
        }
        if ((t & 63) == 0) {
            int wv = t >> 6;
            sred[wv * 4 + 0] = t1a; sred[wv * 4 + 1] = t1b;
            sred[wv * 4 + 2] = nea; sred[wv * 4 + 3] = neb;
        }
    }
    __syncthreads();
    if (t == 0) {
        float4 v = make_float4(sred[0] + sred[4], sred[1] + sred[5],
                               sred[2] + sred[6], sred[3] + sred[7]);
        ((float4*)(ws + WSQ_OFF))[b * 128 + r] = v;
    }
}

// finalize (fast path): sum partials, minn (x8 scale fix), IoU, compose.
__global__ void __launch_bounds__(128) kC2(const float* __restrict__ ws,
                                           const float* __restrict__ wh_map,
                                           const float* __restrict__ reg_map,
                                           const float* __restrict__ reg_gt,
                                           const float* __restrict__ wh_gt,
                                           const int* __restrict__ ind,
                                           const int* __restrict__ reg_mask,
                                           float* __restrict__ out) {
    const int b = blockIdx.x, s = blockIdx.y, k = threadIdx.x;
    float mk = (float)reg_mask[b * KK + k];

    // sum 128 row-partials of sumpow (coalesced per row)
    float sum = 0.f;
    {
        const float* base = ws + ((size_t)(b * 128) * 2 + s) * 128 + k;
        #pragma unroll 8
        for (int c = 0; c < 128; ++c) sum += base[(size_t)c * 256];
    }
    float meanp = sum * (1.0f / 16384.0f);
    // minn = 8 * meanp^(-1/9); select so masked k can't NaN
    float c2 = (mk > 0.f) ? 8.0f * exp2f(log2f(meanp) * (-1.0f / 9.0f)) : 0.0f;

    // t1 / nest from wsQ (threads = rows)
    float g1 = 0.f, g2 = 0.f;
    {
        float4 q = ((const float4*)(ws + WSQ_OFF))[b * 128 + k];
        g1 = s ? q.y : q.x;       // t1 component
        g2 = s ? q.w : q.z;       // nest component
        #pragma unroll
        for (int off = 32; off > 0; off >>= 1) {
            g1 += __shfl_down(g1, off, 64);
            g2 += __shfl_down(g2, off, 64);
        }
    }
    __shared__ float st1[2], sne[2];
    if ((k & 63) == 0) { st1[k >> 6] = g1; sne[k >> 6] = g2; }

    // bounded IoU
    int idx = ind[b * KK + k];
    size_t sb = (size_t)(s * BB + b);
    float rp0 = reg_map[(sb * 2 + 0) * HWSZ + idx];
    float rp1 = reg_map[(sb * 2 + 1) * HWSZ + idx];
    float wp0 = wh_map[(sb * 2 + 0) * HWSZ + idx];
    float wp1 = wh_map[(sb * 2 + 1) * HWSZ + idx];
    float rg0 = reg_gt[(b * KK + k) * 2 + 0];
    float rg1 = reg_gt[(b * KK + k) * 2 + 1];
    float wg0 = wh_gt[(b * KK + k) * 2 + 0];
    float wg1 = wh_gt[(b * KK + k) * 2 + 1];
    float adx = fabsf(rg0 - rp0), ady = fabsf(rg1 - rp1);
    float ldx = 1.0f - fmaxf((wg0 - 2.0f * adx) / (wg0 + 2.0f * adx + EPSF), 0.0f);
    float ldy = 1.0f - fmaxf((wg1 - 2.0f * ady) / (wg1 + 2.0f * ady + EPSF), 0.0f);
    float ldw = 1.0f - fminf(wg0 / (wp0 + EPSF), wp0 / (wg0 + EPSF));
    float ldh = 1.0f - fminf(wg1 / (wp1 + EPSF), wp1 / (wg1 + EPSF));
    float lsum = (smoothl1(ldx) + smoothl1(ldy) + smoothl1(ldw) + smoothl1(ldh)) * mk;

    #pragma unroll
    for (int off = 32; off > 0; off >>= 1) {
        c2   += __shfl_down(c2, off, 64);
        lsum += __shfl_down(lsum, off, 64);
        mk   += __shfl_down(mk, off, 64);
    }
    __shared__ float sred[6];
    int lane = k & 63, wv = k >> 6;
    if (lane == 0) { sred[wv * 3 + 0] = c2; sred[wv * 3 + 1] = lsum; sred[wv * 3 + 2] = mk; }
    __syncthreads();
    if (k == 0) {
        float C2 = sred[0] + sred[3];
        float LS = sred[1] + sred[4];
        float MS = sred[2] + sred[5];
        float t1n = st1[0] + st1[1];
        float nst = sne[0] + sne[1];
        float valid = (MS > 0.f) ? 1.f : 0.f;
        float den = fmaxf(MS, 1.f);
        float t1 = t1n / (nst + EPSF);
        float t2 = C2 / den;
        float hmterm  = (t1 + t2) * valid * (1.0f / 32.0f);
        float iouterm = (LS / (den * 4.0f)) * valid * (1.0f / 32.0f);
        atomicAdd(&out[1], hmterm);
        atomicAdd(&out[2], iouterm);
        atomicAdd(&out[0], hmterm + 0.1f * iouterm);
    }
}

// ============== fallback path (R4, atomic, 3 launches) ===================

__global__ void kzero(float* ws, float* out) {
    int i = blockIdx.x * 256 + threadIdx.x;
    if (i < 4160) ws[i] = 0.0f;
    if (i < 3) out[i] = 0.0f;
}

__global__ void __launch_bounds__(256) kAB(const float* __restrict__ hm,
                                           const int* __restrict__ ctr,
                                           const int* __restrict__ reg_mask,
                                           float* __restrict__ ws) {
    const int b = blockIdx.y;
    const int chunk = blockIdx.x;
    const int base = chunk * 256;
    const int tid = threadIdx.x;
    __shared__ float2 spp[256];
    __shared__ float2 spts_raw[KK];
    __shared__ float2 spts_msk[KK];
    __shared__ float red0[KK], red1[KK];

    float p0 = sigclip(hm[(size_t)(0 * BB + b) * HWSZ + base + tid]);
    float p1 = sigclip(hm[(size_t)(1 * BB + b) * HWSZ + base + tid]);
    spp[tid] = make_float2(p0, p1);
    if (tid < KK) {
        int mk = reg_mask[b * KK + tid];
        float py = (float)ctr[(b * KK + tid) * 2 + 1];
        float px = (float)ctr[(b * KK + tid) * 2 + 0];
        spts_raw[tid] = make_float2(py, px);
        spts_msk[tid] = mk ? make_float2(py, px) : make_float2(1e9f, 1e9f);
    }
    __syncthreads();

    const int k = tid & 127;
    const int half = tid >> 7;
    float2 pt = spts_raw[k];
    float fy1 = (float)(chunk * 2 + half);
    float dy2 = (fy1 - pt.x) * (fy1 - pt.x);
    float acc0 = 0.f, acc1 = 0.f;
    float dx = -pt.y;
    const float2* sp = &spp[half * 128];
    #pragma unroll 4
    for (int j = 0; j < 128; ++j) {
        float d = __builtin_amdgcn_sqrtf(fmaf(dx, dx, dy2));
        float t = d - MAXD;
        float2 p = sp[j];
        float w0 = fmaf(p.x, t, MAXD) + EPSF;
        float w1 = fmaf(p.y, t, MAXD) + EPSF;
        float a2 = w0 * w0, a4 = a2 * a2, a8 = a4 * a4;
        float b2 = w1 * w1, b4 = b2 * b2, b8 = b4 * b4;
        acc0 += __builtin_amdgcn_rcpf(a8 * w0);
        acc1 += __builtin_amdgcn_rcpf(b8 * w1);
        dx += 1.0f;
    }

    {
        float fy = (float)(chunk * 2 + (tid >> 7));
        float fx = (float)(tid & 127);
        float m0 = MAXD2, m1 = MAXD2, m2 = MAXD2, m3 = MAXD2;
        #pragma unroll 4
        for (int kk = 0; kk < KK; kk += 4) {
            float2 q0 = spts_msk[kk + 0];
            float2 q1 = spts_msk[kk + 1];
            float2 q2 = spts_msk[kk + 2];
            float2 q3 = spts_msk[kk + 3];
            float dy0 = fy - q0.x, dx0 = fx - q0.y;
            float dy1 = fy - q1.x, dx1 = fx - q1.y;
            float dy2_ = fy - q2.x, dx2 = fx - q2.y;
            float dy3 = fy - q3.x, dx3 = fx - q3.y;
            m0 = fminf(m0, fmaf(dx0, dx0, dy0 * dy0));
            m1 = fminf(m1, fmaf(dx1, dx1, dy1 * dy1));
            m2 = fminf(m2, fmaf(dx2, dx2, dy2_ * dy2_));
            m3 = fminf(m3, fmaf(dx3, dx3, dy3 * dy3));
        }
        float dmin = __builtin_amdgcn_sqrtf(fminf(fminf(m0, m1), fminf(m2, m3)));
        float t1a = p0 * dmin, t1b = p1 * dmin, nea = p0, neb = p1;
        #pragma unroll
        for (int off = 32; off > 0; off >>= 1) {
            t1a += __shfl_down(t1a, off, 64);
            t1b += __shfl_down(t1b, off, 64);
            nea += __shfl_down(nea, off, 64);
            neb += __shfl_down(neb, off, 64);
        }
        if ((tid & 63) == 0) {
            atomicAdd(&ws[4096 + 0 * BB + b], t1a);
            atomicAdd(&ws[4096 + 1 * BB + b], t1b);
            atomicAdd(&ws[4128 + 0 * BB + b], nea);
            atomicAdd(&ws[4128 + 1 * BB + b], neb);
        }
    }

    if (half) { red0[k] = acc0; red1[k] = acc1; }
    __syncthreads();
    if (!half) {
        atomicAdd(&ws[(0 * BB + b) * KK + k], acc0 + red0[k]);
        atomicAdd(&ws[(1 * BB + b) * KK + k], acc1 + red1[k]);
    }
}

__global__ void __launch_bounds__(128) kC(const float* __restrict__ ws,
                                          const float* __restrict__ wh_map,
                                          const float* __restrict__ reg_map,
                                          const float* __restrict__ reg_gt,
                                          const float* __restrict__ wh_gt,
                                          const int* __restrict__ ind,
                                          const int* __restrict__ reg_mask,
                                          float* __restrict__ out) {
    const int b = blockIdx.x, s = blockIdx.y, k = threadIdx.x;
    float mk = (float)reg_mask[b * KK + k];
    float sp = ws[(s * BB + b) * KK + k];
    float mean = sp * (1.0f / 16384.0f);
    float c2 = (mk > 0.f) ? exp2f(log2f(mean) * (-1.0f / 9.0f)) : 0.0f;

    int idx = ind[b * KK + k];
    size_t sb = (size_t)(s * BB + b);
    float rp0 = reg_map[(sb * 2 + 0) * HWSZ + idx];
    float rp1 = reg_map[(sb * 2 + 1) * HWSZ + idx];
    float wp0 = wh_map[(sb * 2 + 0) * HWSZ + idx];
    float wp1 = wh_map[(sb * 2 + 1) * HWSZ + idx];
    float rg0 = reg_gt[(b * KK + k) * 2 + 0];
    float rg1 = reg_gt[(b * KK + k) * 2 + 1];
    float wg0 = wh_gt[(b * KK + k) * 2 + 0];
    float wg1 = wh_gt[(b * KK + k) * 2 + 1];
    float adx = fabsf(rg0 - rp0), ady = fabsf(rg1 - rp1);
    float ldx = 1.0f - fmaxf((wg0 - 2.0f * adx) / (wg0 + 2.0f * adx + EPSF), 0.0f);
    float ldy = 1.0f - fmaxf((wg1 - 2.0f * ady) / (wg1 + 2.0f * ady + EPSF), 0.0f);
    float ldw = 1.0f - fminf(wg0 / (wp0 + EPSF), wp0 / (wg0 + EPSF));
    float ldh = 1.0f - fminf(wg1 / (wp1 + EPSF), wp1 / (wg1 + EPSF));
    float lsum = (smoothl1(ldx) + smoothl1(ldy) + smoothl1(ldw) + smoothl1(ldh)) * mk;

    #pragma unroll
    for (int off = 32; off > 0; off >>= 1) {
        c2   += __shfl_down(c2, off, 64);
        lsum += __shfl_down(lsum, off, 64);
        mk   += __shfl_down(mk, off, 64);
    }
    __shared__ float sred[6];
    int lane = k & 63, wv = k >> 6;
    if (lane == 0) { sred[wv * 3 + 0] = c2; sred[wv * 3 + 1] = lsum; sred[wv * 3 + 2] = mk; }
    __syncthreads();
    if (k == 0) {
        float C2 = sred[0] + sred[3];
        float LS = sred[1] + sred[4];
        float MS = sred[2] + sred[5];
        float valid = (MS > 0.f) ? 1.f : 0.f;
        float den = fmaxf(MS, 1.f);
        float t1 = ws[4096 + s * BB + b] / (ws[4128 + s * BB + b] + EPSF);
        float t2 = C2 / den;
        float hmterm  = (t1 + t2) * valid * (1.0f / 32.0f);
        float iouterm = (LS / (den * 4.0f)) * valid * (1.0f / 32.0f);
        atomicAdd(&out[1], hmterm);
        atomicAdd(&out[2], iouterm);
        atomicAdd(&out[0], hmterm + 0.1f * iouterm);
    }
}

extern "C" void kernel_launch(void* const* d_in, const int* in_sizes, int n_in,
                              void* d_out, int out_size, void* d_ws, size_t ws_size,
                              hipStream_t stream) {
    const float* hm       = (const float*)d_in[0];
    const float* wh_map   = (const float*)d_in[1];
    const float* reg_map  = (const float*)d_in[2];
    const float* reg_gt   = (const float*)d_in[3];
    const float* wh_gt    = (const float*)d_in[4];
    const int*   ind      = (const int*)d_in[5];
    const int*   ctr      = (const int*)d_in[6];
    const int*   reg_mask = (const int*)d_in[7];
    float* out = (float*)d_out;
    float* ws  = (float*)d_ws;

    if (ws_size >= WS_NEEDED_BYTES) {
        hipLaunchKernelGGL(kAB2, dim3(128, BB), dim3(256), 0, stream,
                           hm, ctr, reg_mask, ws, out);
        hipLaunchKernelGGL(kC2, dim3(BB, SS), dim3(128), 0, stream,
                           ws, wh_map, reg_map, reg_gt, wh_gt, ind, reg_mask, out);
    } else {
        hipLaunchKernelGGL(kzero, dim3(17), dim3(256), 0, stream, ws, out);
        hipLaunchKernelGGL(kAB, dim3(64, BB), dim3(256), 0, stream, hm, ctr, reg_mask, ws);
        hipLaunchKernelGGL(kC, dim3(BB, SS), dim3(128), 0, stream,
                           ws, wh_map, reg_map, reg_gt, wh_gt, ind, reg_mask, out);
    }
}

// Round 6
// 94.274 us; speedup vs baseline: 1.9500x; 1.0360x over previous
//
#include <hip/hip_runtime.h>

#define SS 2
#define BB 16
#define KK 128
#define HH 128
#define WW 128
#define HWSZ (HH*WW)
#define EPSF 1e-6f
#define MAXD 181.01933598375618f
#define MAXD2 32768.0f
#define MAXD8 (181.01933598375618f * 0.125f)
#define ME8C ((181.01933598375618f + 1e-6f) * 0.125f)

typedef float v2f __attribute__((ext_vector_type(2)));

// ---------------- partial-slot (no-atomic) path layout -------------------
// wsP: [0, 524288) floats: sumpow partial  ws[((b*128 + row)*2 + s)*128 + k]
// wsQ: [524288, 532480): float4 per (b,row): {t1a, t1b, nea, neb}
#define WSQ_OFF 524288
#define WS_NEEDED_BYTES ((size_t)(524288 + 16*128*4) * 4)

__device__ __forceinline__ float sigclip(float x) {
    float e = __expf(-x);
    float p = __builtin_amdgcn_rcpf(1.0f + e);
    return fminf(fmaxf(p, 1e-4f), 0.9999f);
}

__device__ __forceinline__ float smoothl1(float l) {
    return (l < 0.2f) ? (2.5f * l * l) : (l - 0.1f);
}

// ======================= fast path: 2 launches ===========================

// One block per (b, row). 256 threads.
// Phase 1 (term2): thread=(k, col-half), 64 cols each; reciprocal-pairing:
//   1/a9 + 1/b9 = (a9+b9) * rcp(a9*b9)  -> 2 rcp/iter instead of 4.
// Phase 2 (term1): thread=(pixel, k-half), 64 pts each, MASKED pts.
__global__ void __launch_bounds__(256, 6) kAB2(const float* __restrict__ hm,
                                               const int* __restrict__ ctr,
                                               const int* __restrict__ reg_mask,
                                               float* __restrict__ ws,
                                               float* __restrict__ out) {
    const int r = blockIdx.x;            // row 0..127
    const int b = blockIdx.y;
    const int t = threadIdx.x;
    __shared__ __align__(16) float spp2[128][2];   // [col][channel]
    __shared__ float2 spts_raw[KK];
    __shared__ float2 spts_msk[KK];
    __shared__ float red0[KK], red1[KK];
    __shared__ float st2[128];
    __shared__ float sred[8];

    if (r == 0 && b == 0 && t < 3) out[t] = 0.0f;   // zero out for kC2 (stream-ordered)

    {   // stage probs: thread t -> channel c=t>>7, column j=t&127
        int c = t >> 7, j = t & 127;
        spp2[j][c] = sigclip(hm[(size_t)(c * BB + b) * HWSZ + r * WW + j]);
    }
    if (t < KK) {
        int mk = reg_mask[b * KK + t];
        float py = (float)ctr[(b * KK + t) * 2 + 1];   // pts = ctr[...,::-1]
        float px = (float)ctr[(b * KK + t) * 2 + 0];
        spts_raw[t] = make_float2(py, px);
        spts_msk[t] = mk ? make_float2(py, px) : make_float2(1e9f, 1e9f);
    }
    __syncthreads();

    const int k = t & 127;
    const int h = t >> 7;

    // ---- phase 1: coords pre-scaled by 0.125; w' = 0.125*(weighted+EPS)
    float acc0 = 0.f, acc1 = 0.f;
    {
        float2 pt = spts_raw[k];
        float dy = ((float)r - pt.x) * 0.125f;
        float dy2 = dy * dy;
        float dx = ((float)(h * 64) - pt.y) * 0.125f;
        const float4* sp4 = (const float4*)(&spp2[h * 64][0]);   // 2 cols per float4
        const v2f ME8V = {ME8C, ME8C};
        #pragma unroll 4
        for (int q = 0; q < 32; ++q) {
            float4 pq = sp4[q];
            float dA = __builtin_amdgcn_sqrtf(fmaf(dx, dx, dy2));
            float dxB = dx + 0.125f;
            float dB = __builtin_amdgcn_sqrtf(fmaf(dxB, dxB, dy2));
            float tA = dA - MAXD8;
            float tB = dB - MAXD8;
            v2f pA = {pq.x, pq.y};
            v2f pB = {pq.z, pq.w};
            v2f wA = pA * tA + ME8V;     // -> v_pk_fma_f32
            v2f wB = pB * tB + ME8V;
            v2f a2 = wA * wA, a4 = a2 * a2, a8 = a4 * a4, a9 = a8 * wA;
            v2f b2 = wB * wB, b4 = b2 * b2, b8 = b4 * b4, b9 = b8 * wB;
            v2f pr = a9 * b9;            // pairing: product & sum per channel
            v2f sm = a9 + b9;
            acc0 = fmaf(sm.x, __builtin_amdgcn_rcpf(pr.x), acc0);
            acc1 = fmaf(sm.y, __builtin_amdgcn_rcpf(pr.y), acc1);
            dx += 0.25f;
        }
    }

    // ---- phase 2: half the k-range per thread (unscaled coords)
    float mm;
    {
        int pix = t & 127;
        float fx = (float)pix, fyf = (float)r;
        float m0 = MAXD2, m1 = MAXD2, m2 = MAXD2, m3 = MAXD2;
        int kb = h * 64;
        #pragma unroll 4
        for (int kk = 0; kk < 64; kk += 4) {
            float2 q0 = spts_msk[kb + kk + 0];
            float2 q1 = spts_msk[kb + kk + 1];
            float2 q2 = spts_msk[kb + kk + 2];
            float2 q3 = spts_msk[kb + kk + 3];
            float e0 = fyf - q0.x, f0 = fx - q0.y;
            float e1 = fyf - q1.x, f1 = fx - q1.y;
            float e2 = fyf - q2.x, f2 = fx - q2.y;
            float e3 = fyf - q3.x, f3 = fx - q3.y;
            m0 = fminf(m0, fmaf(f0, f0, e0 * e0));
            m1 = fminf(m1, fmaf(f1, f1, e1 * e1));
            m2 = fminf(m2, fmaf(f2, f2, e2 * e2));
            m3 = fminf(m3, fmaf(f3, f3, e3 * e3));
        }
        mm = fminf(fminf(m0, m1), fminf(m2, m3));
    }

    if (t >= 128) { st2[k] = mm; red0[k] = acc0; red1[k] = acc1; }
    __syncthreads();

    if (t < 128) {
        // sumpow partial store (coalesced over k)
        float s0 = acc0 + red0[k];
        float s1 = acc1 + red1[k];
        size_t basep = ((size_t)(b * 128 + r) * 2) * 128;
        ws[basep + k] = s0;
        ws[basep + 128 + k] = s1;
        // term1
        float dmin = __builtin_amdgcn_sqrtf(fminf(mm, st2[k]));
        float p0 = spp2[k][0], p1 = spp2[k][1];
        float t1a = p0 * dmin, t1b = p1 * dmin, nea = p0, neb = p1;
        #pragma unroll
        for (int off = 32; off > 0; off >>= 1) {
            t1a += __shfl_down(t1a, off, 64);
            t1b += __shfl_down(t1b, off, 64);
            nea += __shfl_down(nea, off, 64);
            neb += __shfl_down(neb, off, 64);
        }
        if ((t & 63) == 0) {
            int wv = t >> 6;
            sred[wv * 4 + 0] = t1a; sred[wv * 4 + 1] = t1b;
            sred[wv * 4 + 2] = nea; sred[wv * 4 + 3] = neb;
        }
    }
    __syncthreads();
    if (t == 0) {
        float4 v = make_float4(sred[0] + sred[4], sred[1] + sred[5],
                               sred[2] + sred[6], sred[3] + sred[7]);
        ((float4*)(ws + WSQ_OFF))[b * 128 + r] = v;
    }
}

// finalize (fast path): sum partials (split across 2 thread-groups), minn,
// IoU, compose. One block per (s,b), 256 threads.
__global__ void __launch_bounds__(256) kC2(const float* __restrict__ ws,
                                           const float* __restrict__ wh_map,
                                           const float* __restrict__ reg_map,
                                           const float* __restrict__ reg_gt,
                                           const float* __restrict__ wh_gt,
                                           const int* __restrict__ ind,
                                           const int* __restrict__ reg_mask,
                                           float* __restrict__ out) {
    const int b = blockIdx.x, s = blockIdx.y;
    const int t = threadIdx.x;
    const int k = t & 127;
    const int g = t >> 7;                 // row half

    __shared__ float ssum[256];
    // sum 64 row-partials of sumpow per thread (coalesced over k each step)
    {
        float sum = 0.f;
        const float* base = ws + ((size_t)(b * 128 + g * 64) * 2 + s) * 128 + k;
        #pragma unroll 8
        for (int c = 0; c < 64; ++c) sum += base[(size_t)c * 256];
        ssum[t] = sum;
    }
    __syncthreads();
    if (t >= 128) return;

    float mk = (float)reg_mask[b * KK + k];
    float meanp = (ssum[k] + ssum[k + 128]) * (1.0f / 16384.0f);
    // minn = 8 * meanp^(-1/9); select so masked k can't NaN
    float c2 = (mk > 0.f) ? 8.0f * exp2f(log2f(meanp) * (-1.0f / 9.0f)) : 0.0f;

    // t1 / nest from wsQ (threads = rows)
    float g1 = 0.f, g2 = 0.f;
    {
        float4 q = ((const float4*)(ws + WSQ_OFF))[b * 128 + k];
        g1 = s ? q.y : q.x;       // t1 component
        g2 = s ? q.w : q.z;       // nest component
        #pragma unroll
        for (int off = 32; off > 0; off >>= 1) {
            g1 += __shfl_down(g1, off, 64);
            g2 += __shfl_down(g2, off, 64);
        }
    }
    __shared__ float st1[2], sne[2];
    if ((k & 63) == 0) { st1[k >> 6] = g1; sne[k >> 6] = g2; }

    // bounded IoU
    int idx = ind[b * KK + k];
    size_t sb = (size_t)(s * BB + b);
    float rp0 = reg_map[(sb * 2 + 0) * HWSZ + idx];
    float rp1 = reg_map[(sb * 2 + 1) * HWSZ + idx];
    float wp0 = wh_map[(sb * 2 + 0) * HWSZ + idx];
    float wp1 = wh_map[(sb * 2 + 1) * HWSZ + idx];
    float rg0 = reg_gt[(b * KK + k) * 2 + 0];
    float rg1 = reg_gt[(b * KK + k) * 2 + 1];
    float wg0 = wh_gt[(b * KK + k) * 2 + 0];
    float wg1 = wh_gt[(b * KK + k) * 2 + 1];
    float adx = fabsf(rg0 - rp0), ady = fabsf(rg1 - rp1);
    float ldx = 1.0f - fmaxf((wg0 - 2.0f * adx) / (wg0 + 2.0f * adx + EPSF), 0.0f);
    float ldy = 1.0f - fmaxf((wg1 - 2.0f * ady) / (wg1 + 2.0f * ady + EPSF), 0.0f);
    float ldw = 1.0f - fminf(wg0 / (wp0 + EPSF), wp0 / (wg0 + EPSF));
    float ldh = 1.0f - fminf(wg1 / (wp1 + EPSF), wp1 / (wg1 + EPSF));
    float lsum = (smoothl1(ldx) + smoothl1(ldy) + smoothl1(ldw) + smoothl1(ldh)) * mk;

    #pragma unroll
    for (int off = 32; off > 0; off >>= 1) {
        c2   += __shfl_down(c2, off, 64);
        lsum += __shfl_down(lsum, off, 64);
        mk   += __shfl_down(mk, off, 64);
    }
    __shared__ float sred[6];
    int lane = k & 63, wv = k >> 6;
    if (lane == 0) { sred[wv * 3 + 0] = c2; sred[wv * 3 + 1] = lsum; sred[wv * 3 + 2] = mk; }
    __syncthreads();
    if (k == 0) {
        float C2 = sred[0] + sred[3];
        float LS = sred[1] + sred[4];
        float MS = sred[2] + sred[5];
        float t1n = st1[0] + st1[1];
        float nst = sne[0] + sne[1];
        float valid = (MS > 0.f) ? 1.f : 0.f;
        float den = fmaxf(MS, 1.f);
        float t1 = t1n / (nst + EPSF);
        float t2 = C2 / den;
        float hmterm  = (t1 + t2) * valid * (1.0f / 32.0f);
        float iouterm = (LS / (den * 4.0f)) * valid * (1.0f / 32.0f);
        atomicAdd(&out[1], hmterm);
        atomicAdd(&out[2], iouterm);
        atomicAdd(&out[0], hmterm + 0.1f * iouterm);
    }
}

// ============== fallback path (R4, atomic, 3 launches) ===================

__global__ void kzero(float* ws, float* out) {
    int i = blockIdx.x * 256 + threadIdx.x;
    if (i < 4160) ws[i] = 0.0f;
    if (i < 3) out[i] = 0.0f;
}

__global__ void __launch_bounds__(256) kAB(const float* __restrict__ hm,
                                           const int* __restrict__ ctr,
                                           const int* __restrict__ reg_mask,
                                           float* __restrict__ ws) {
    const int b = blockIdx.y;
    const int chunk = blockIdx.x;
    const int base = chunk * 256;
    const int tid = threadIdx.x;
    __shared__ float2 spp[256];
    __shared__ float2 spts_raw[KK];
    __shared__ float2 spts_msk[KK];
    __shared__ float red0[KK], red1[KK];

    float p0 = sigclip(hm[(size_t)(0 * BB + b) * HWSZ + base + tid]);
    float p1 = sigclip(hm[(size_t)(1 * BB + b) * HWSZ + base + tid]);
    spp[tid] = make_float2(p0, p1);
    if (tid < KK) {
        int mk = reg_mask[b * KK + tid];
        float py = (float)ctr[(b * KK + tid) * 2 + 1];
        float px = (float)ctr[(b * KK + tid) * 2 + 0];
        spts_raw[tid] = make_float2(py, px);
        spts_msk[tid] = mk ? make_float2(py, px) : make_float2(1e9f, 1e9f);
    }
    __syncthreads();

    const int k = tid & 127;
    const int half = tid >> 7;
    float2 pt = spts_raw[k];
    float fy1 = (float)(chunk * 2 + half);
    float dy2 = (fy1 - pt.x) * (fy1 - pt.x);
    float acc0 = 0.f, acc1 = 0.f;
    float dx = -pt.y;
    const float2* sp = &spp[half * 128];
    #pragma unroll 4
    for (int j = 0; j < 128; ++j) {
        float d = __builtin_amdgcn_sqrtf(fmaf(dx, dx, dy2));
        float t = d - MAXD;
        float2 p = sp[j];
        float w0 = fmaf(p.x, t, MAXD) + EPSF;
        float w1 = fmaf(p.y, t, MAXD) + EPSF;
        float a2 = w0 * w0, a4 = a2 * a2, a8 = a4 * a4;
        float b2 = w1 * w1, b4 = b2 * b2, b8 = b4 * b4;
        acc0 += __builtin_amdgcn_rcpf(a8 * w0);
        acc1 += __builtin_amdgcn_rcpf(b8 * w1);
        dx += 1.0f;
    }

    {
        float fy = (float)(chunk * 2 + (tid >> 7));
        float fx = (float)(tid & 127);
        float m0 = MAXD2, m1 = MAXD2, m2 = MAXD2, m3 = MAXD2;
        #pragma unroll 4
        for (int kk = 0; kk < KK; kk += 4) {
            float2 q0 = spts_msk[kk + 0];
            float2 q1 = spts_msk[kk + 1];
            float2 q2 = spts_msk[kk + 2];
            float2 q3 = spts_msk[kk + 3];
            float dy0 = fy - q0.x, dx0 = fx - q0.y;
            float dy1 = fy - q1.x, dx1 = fx - q1.y;
            float dy2_ = fy - q2.x, dx2 = fx - q2.y;
            float dy3 = fy - q3.x, dx3 = fx - q3.y;
            m0 = fminf(m0, fmaf(dx0, dx0, dy0 * dy0));
            m1 = fminf(m1, fmaf(dx1, dx1, dy1 * dy1));
            m2 = fminf(m2, fmaf(dx2, dx2, dy2_ * dy2_));
            m3 = fminf(m3, fmaf(dx3, dx3, dy3 * dy3));
        }
        float dmin = __builtin_amdgcn_sqrtf(fminf(fminf(m0, m1), fminf(m2, m3)));
        float t1a = p0 * dmin, t1b = p1 * dmin, nea = p0, neb = p1;
        #pragma unroll
        for (int off = 32; off > 0; off >>= 1) {
            t1a += __shfl_down(t1a, off, 64);
            t1b += __shfl_down(t1b, off, 64);
            nea += __shfl_down(nea, off, 64);
            neb += __shfl_down(neb, off, 64);
        }
        if ((tid & 63) == 0) {
            atomicAdd(&ws[4096 + 0 * BB + b], t1a);
            atomicAdd(&ws[4096 + 1 * BB + b], t1b);
            atomicAdd(&ws[4128 + 0 * BB + b], nea);
            atomicAdd(&ws[4128 + 1 * BB + b], neb);
        }
    }

    if (half) { red0[k] = acc0; red1[k] = acc1; }
    __syncthreads();
    if (!half) {
        atomicAdd(&ws[(0 * BB + b) * KK + k], acc0 + red0[k]);
        atomicAdd(&ws[(1 * BB + b) * KK + k], acc1 + red1[k]);
    }
}

__global__ void __launch_bounds__(128) kC(const float* __restrict__ ws,
                                          const float* __restrict__ wh_map,
                                          const float* __restrict__ reg_map,
                                          const float* __restrict__ reg_gt,
                                          const float* __restrict__ wh_gt,
                                          const int* __restrict__ ind,
                                          const int* __restrict__ reg_mask,
                                          float* __restrict__ out) {
    const int b = blockIdx.x, s = blockIdx.y, k = threadIdx.x;
    float mk = (float)reg_mask[b * KK + k];
    float sp = ws[(s * BB + b) * KK + k];
    float mean = sp * (1.0f / 16384.0f);
    float c2 = (mk > 0.f) ? exp2f(log2f(mean) * (-1.0f / 9.0f)) : 0.0f;

    int idx = ind[b * KK + k];
    size_t sb = (size_t)(s * BB + b);
    float rp0 = reg_map[(sb * 2 + 0) * HWSZ + idx];
    float rp1 = reg_map[(sb * 2 + 1) * HWSZ + idx];
    float wp0 = wh_map[(sb * 2 + 0) * HWSZ + idx];
    float wp1 = wh_map[(sb * 2 + 1) * HWSZ + idx];
    float rg0 = reg_gt[(b * KK + k) * 2 + 0];
    float rg1 = reg_gt[(b * KK + k) * 2 + 1];
    float wg0 = wh_gt[(b * KK + k) * 2 + 0];
    float wg1 = wh_gt[(b * KK + k) * 2 + 1];
    float adx = fabsf(rg0 - rp0), ady = fabsf(rg1 - rp1);
    float ldx = 1.0f - fmaxf((wg0 - 2.0f * adx) / (wg0 + 2.0f * adx + EPSF), 0.0f);
    float ldy = 1.0f - fmaxf((wg1 - 2.0f * ady) / (wg1 + 2.0f * ady + EPSF), 0.0f);
    float ldw = 1.0f - fminf(wg0 / (wp0 + EPSF), wp0 / (wg0 + EPSF));
    float ldh = 1.0f - fminf(wg1 / (wp1 + EPSF), wp1 / (wg1 + EPSF));
    float lsum = (smoothl1(ldx) + smoothl1(ldy) + smoothl1(ldw) + smoothl1(ldh)) * mk;

    #pragma unroll
    for (int off = 32; off > 0; off >>= 1) {
        c2   += __shfl_down(c2, off, 64);
        lsum += __shfl_down(lsum, off, 64);
        mk   += __shfl_down(mk, off, 64);
    }
    __shared__ float sred[6];
    int lane = k & 63, wv = k >> 6;
    if (lane == 0) { sred[wv * 3 + 0] = c2; sred[wv * 3 + 1] = lsum; sred[wv * 3 + 2] = mk; }
    __syncthreads();
    if (k == 0) {
        float C2 = sred[0] + sred[3];
        float LS = sred[1] + sred[4];
        float MS = sred[2] + sred[5];
        float valid = (MS > 0.f) ? 1.f : 0.f;
        float den = fmaxf(MS, 1.f);
        float t1 = ws[4096 + s * BB + b] / (ws[4128 + s * BB + b] + EPSF);
        float t2 = C2 / den;
        float hmterm  = (t1 + t2) * valid * (1.0f / 32.0f);
        float iouterm = (LS / (den * 4.0f)) * valid * (1.0f / 32.0f);
        atomicAdd(&out[1], hmterm);
        atomicAdd(&out[2], iouterm);
        atomicAdd(&out[0], hmterm + 0.1f * iouterm);
    }
}

extern "C" void kernel_launch(void* const* d_in, const int* in_sizes, int n_in,
                              void* d_out, int out_size, void* d_ws, size_t ws_size,
                              hipStream_t stream) {
    const float* hm       = (const float*)d_in[0];
    const float* wh_map   = (const float*)d_in[1];
    const float* reg_map  = (const float*)d_in[2];
    const float* reg_gt   = (const float*)d_in[3];
    const float* wh_gt    = (const float*)d_in[4];
    const int*   ind      = (const int*)d_in[5];
    const int*   ctr      = (const int*)d_in[6];
    const int*   reg_mask = (const int*)d_in[7];
    float* out = (float*)d_out;
    float* ws  = (float*)d_ws;

    if (ws_size >= WS_NEEDED_BYTES) {
        hipLaunchKernelGGL(kAB2, dim3(128, BB), dim3(256), 0, stream,
                           hm, ctr, reg_mask, ws, out);
        hipLaunchKernelGGL(kC2, dim3(BB, SS), dim3(256), 0, stream,
                           ws, wh_map, reg_map, reg_gt, wh_gt, ind, reg_mask, out);
    } else {
        hipLaunchKernelGGL(kzero, dim3(17), dim3(256), 0, stream, ws, out);
        hipLaunchKernelGGL(kAB, dim3(64, BB), dim3(256), 0, stream, hm, ctr, reg_mask, ws);
        hipLaunchKernelGGL(kC, dim3(BB, SS), dim3(128), 0, stream,
                           ws, wh_map, reg_map, reg_gt, wh_gt, ind, reg_mask, out);
    }
}